// Round 1
// baseline (358.316 us; speedup 1.0000x reference)
//
#include <hip/hip_runtime.h>

#define NXg 64
#define NYg 64
#define NZg 64
#define N_PMT 180
#define N_CLUSTERS 128
#define BPC 16            // blocks per cluster
#define BLOCK 256
#define NWAVE (BLOCK / 64)

// Workspace layout (d_ws):
//   int   offsets[N_CLUSTERS + 1]
//   float dxc[N_CLUSTERS]

__global__ void prep_kernel(const float* __restrict__ dx,
                            const int* __restrict__ sizes,
                            const float* __restrict__ dx_ranges,
                            int* __restrict__ offsets,
                            float* __restrict__ dxc,
                            float* __restrict__ out) {
    int t = threadIdx.x;
    if (t < N_CLUSTERS) {
        float lo = dx_ranges[2 * t];
        float hi = dx_ranges[2 * t + 1];
        float v  = dx[t];
        dxc[t] = fminf(fmaxf(v, lo), hi);
    }
    // zero the output (harness poisons it to 0xAA before every launch)
    for (int i = t; i < N_CLUSTERS * N_PMT; i += BLOCK) out[i] = 0.f;
    if (t == 0) {
        int acc = 0;
        for (int c = 0; c < N_CLUSTERS; ++c) { offsets[c] = acc; acc += sizes[c]; }
        offsets[N_CLUSTERS] = acc;
    }
}

__global__ __launch_bounds__(BLOCK) void gather_kernel(
    const float4* __restrict__ batch,
    const float*  __restrict__ vis,
    const int*    __restrict__ offsets,
    const float*  __restrict__ dxc,
    float* __restrict__ out) {

    const int b    = blockIdx.x;
    const int c    = b / BPC;
    const int sub  = b % BPC;
    const int start = offsets[c];
    const int end   = offsets[c + 1];
    const int count = end - start;
    const int chunk = (count + BPC - 1) / BPC;
    const int s0 = start + sub * chunk;
    const int s1 = min(s0 + chunk, end);

    const int wave = threadIdx.x >> 6;
    const int lane = threadIdx.x & 63;

    const int wtotal = s1 - s0;
    const int per = (wtotal + NWAVE - 1) / NWAVE;
    const int ws0 = s0 + wave * per;
    const int ws1 = min(ws0 + per, s1);

    const float dxc_c = dxc[c];

    float acc0 = 0.f, acc1 = 0.f, acc2 = 0.f;

    for (int base = ws0; base < ws1; base += 64) {
        const int p = base + lane;
        float q = 0.f;
        int vox = 0;
        if (p < ws1) {
            float4 pd = batch[p];
            float x = pd.x + dxc_c;
            int ix = (int)floorf(x);
            int iy = (int)floorf(pd.y);
            int iz = (int)floorf(pd.z);
            ix = max(0, min(NXg - 1, ix));
            iy = max(0, min(NYg - 1, iy));
            iz = max(0, min(NZg - 1, iz));
            vox = ix + NXg * (iy + NYg * iz);
            q = pd.w;
        }
        #pragma unroll
        for (int j = 0; j < 64; ++j) {
            const int   v  = __shfl(vox, j);
            const float qj = __shfl(q, j);
            const float* row = vis + (size_t)v * N_PMT;
            float v0 = row[lane];
            float v1 = row[lane + 64];
            float v2 = 0.f;
            if (lane < N_PMT - 128) v2 = row[lane + 128];
            acc0 = fmaf(v0, qj, acc0);
            acc1 = fmaf(v1, qj, acc1);
            acc2 = fmaf(v2, qj, acc2);
        }
    }

    // block-level reduction in LDS, then one atomic per PMT per block
    __shared__ float sacc[N_PMT];
    for (int i = threadIdx.x; i < N_PMT; i += BLOCK) sacc[i] = 0.f;
    __syncthreads();
    atomicAdd(&sacc[lane], acc0);
    atomicAdd(&sacc[lane + 64], acc1);
    if (lane < N_PMT - 128) atomicAdd(&sacc[lane + 128], acc2);
    __syncthreads();
    for (int i = threadIdx.x; i < N_PMT; i += BLOCK)
        atomicAdd(&out[c * N_PMT + i], sacc[i]);
}

extern "C" void kernel_launch(void* const* d_in, const int* in_sizes, int n_in,
                              void* d_out, int out_size, void* d_ws, size_t ws_size,
                              hipStream_t stream) {
    const float* dx        = (const float*)d_in[0];
    const float* batch     = (const float*)d_in[1];
    const int*   sizes     = (const int*)d_in[2];
    const float* dx_ranges = (const float*)d_in[3];
    const float* vis       = (const float*)d_in[4];
    float* out = (float*)d_out;

    int*   offsets = (int*)d_ws;
    float* dxc     = (float*)((char*)d_ws + sizeof(int) * (N_CLUSTERS + 1));

    prep_kernel<<<1, BLOCK, 0, stream>>>(dx, sizes, dx_ranges, offsets, dxc, out);

    gather_kernel<<<N_CLUSTERS * BPC, BLOCK, 0, stream>>>(
        (const float4*)batch, vis, offsets, dxc, out);
}

// Round 2
// 348.064 us; speedup vs baseline: 1.0295x; 1.0295x over previous
//
#include <hip/hip_runtime.h>

#define N_PMT 180
#define N_PMT4 45          // 180 floats = 45 float4, rows are 16B-aligned (720 = 16*45)
#define N_CLUSTERS 128
#define BPC 16             // blocks per cluster
#define BLOCK 256
#define NWAVE (BLOCK / 64)

// Workspace layout (d_ws):
//   int   offsets[N_CLUSTERS + 1]
//   float dxc[N_CLUSTERS]

__global__ void prep_kernel(const float* __restrict__ dx,
                            const int* __restrict__ sizes,
                            const float* __restrict__ dx_ranges,
                            int* __restrict__ offsets,
                            float* __restrict__ dxc) {
    __shared__ int s[N_CLUSTERS];
    const int t = threadIdx.x;      // 128 threads
    s[t] = sizes[t];
    float lo = dx_ranges[2 * t];
    float hi = dx_ranges[2 * t + 1];
    dxc[t] = fminf(fmaxf(dx[t], lo), hi);
    __syncthreads();
    int acc = 0;
    for (int i = 0; i < t; ++i) acc += s[i];   // LDS reads, parallel across threads
    offsets[t] = acc;
    if (t == N_CLUSTERS - 1) offsets[N_CLUSTERS] = acc + s[t];
}

__global__ __launch_bounds__(BLOCK) void gather_kernel(
    const float4* __restrict__ batch,
    const float4* __restrict__ vis4,
    const int*    __restrict__ offsets,
    const float*  __restrict__ dxc,
    float* __restrict__ out) {

    const int b     = blockIdx.x;
    const int c     = b / BPC;
    const int sub   = b % BPC;
    const int start = offsets[c];
    const int end   = offsets[c + 1];
    const int count = end - start;
    const int chunk = (count + BPC - 1) / BPC;
    const int s0 = start + sub * chunk;
    const int s1 = min(s0 + chunk, end);

    const int wave = threadIdx.x >> 6;
    const int lane = threadIdx.x & 63;

    const int wtotal = s1 - s0;
    const int per = (wtotal + NWAVE - 1) / NWAVE;
    const int ws0 = s0 + wave * per;
    const int ws1 = min(ws0 + per, s1);

    const float dxc_c = dxc[c];
    const bool active = (lane < N_PMT4);

    float4 accE = {0.f, 0.f, 0.f, 0.f};
    float4 accO = {0.f, 0.f, 0.f, 0.f};

    for (int base = ws0; base < ws1; base += 64) {
        const int p = base + lane;
        float q = 0.f;
        int vox = 0;
        if (p < ws1) {
            float4 pd = batch[p];
            float x = pd.x + dxc_c;
            int ix = (int)floorf(x);
            int iy = (int)floorf(pd.y);
            int iz = (int)floorf(pd.z);
            ix = max(0, min(63, ix));
            iy = max(0, min(63, iy));
            iz = max(0, min(63, iz));
            vox = ix + 64 * (iy + 64 * iz);
            q = pd.w;
        }
        #pragma unroll
        for (int j = 0; j < 64; j += 2) {
            // literal-lane readlane -> SGPR broadcast -> scalar row base address
            const int   v0 = __builtin_amdgcn_readlane(vox, j);
            const float q0 = __uint_as_float(__builtin_amdgcn_readlane(__float_as_uint(q), j));
            const int   v1 = __builtin_amdgcn_readlane(vox, j + 1);
            const float q1 = __uint_as_float(__builtin_amdgcn_readlane(__float_as_uint(q), j + 1));
            if (active) {
                float4 r0 = vis4[(size_t)v0 * N_PMT4 + lane];
                float4 r1 = vis4[(size_t)v1 * N_PMT4 + lane];
                accE.x = fmaf(r0.x, q0, accE.x);
                accE.y = fmaf(r0.y, q0, accE.y);
                accE.z = fmaf(r0.z, q0, accE.z);
                accE.w = fmaf(r0.w, q0, accE.w);
                accO.x = fmaf(r1.x, q1, accO.x);
                accO.y = fmaf(r1.y, q1, accO.y);
                accO.z = fmaf(r1.z, q1, accO.z);
                accO.w = fmaf(r1.w, q1, accO.w);
            }
        }
    }

    // block-level reduction in LDS, then one atomic per PMT per block
    __shared__ float sacc[N_PMT];
    for (int i = threadIdx.x; i < N_PMT; i += BLOCK) sacc[i] = 0.f;
    __syncthreads();
    if (active) {
        atomicAdd(&sacc[lane * 4 + 0], accE.x + accO.x);
        atomicAdd(&sacc[lane * 4 + 1], accE.y + accO.y);
        atomicAdd(&sacc[lane * 4 + 2], accE.z + accO.z);
        atomicAdd(&sacc[lane * 4 + 3], accE.w + accO.w);
    }
    __syncthreads();
    for (int i = threadIdx.x; i < N_PMT; i += BLOCK)
        atomicAdd(&out[c * N_PMT + i], sacc[i]);
}

extern "C" void kernel_launch(void* const* d_in, const int* in_sizes, int n_in,
                              void* d_out, int out_size, void* d_ws, size_t ws_size,
                              hipStream_t stream) {
    const float* dx        = (const float*)d_in[0];
    const float* batch     = (const float*)d_in[1];
    const int*   sizes     = (const int*)d_in[2];
    const float* dx_ranges = (const float*)d_in[3];
    const float* vis       = (const float*)d_in[4];
    float* out = (float*)d_out;

    int*   offsets = (int*)d_ws;
    float* dxc     = (float*)((char*)d_ws + sizeof(int) * (N_CLUSTERS + 1));

    // zero output (graph-capturable memset node)
    hipMemsetAsync(out, 0, (size_t)out_size * sizeof(float), stream);

    prep_kernel<<<1, N_CLUSTERS, 0, stream>>>(dx, sizes, dx_ranges, offsets, dxc);

    gather_kernel<<<N_CLUSTERS * BPC, BLOCK, 0, stream>>>(
        (const float4*)batch, (const float4*)vis, offsets, dxc, out);
}

// Round 3
// 347.135 us; speedup vs baseline: 1.0322x; 1.0027x over previous
//
#include <hip/hip_runtime.h>

#define N_PMT 180
#define N_PMT4 45          // 180 floats = 45 float4, rows are 16B-aligned (720 = 16*45)
#define N_CLUSTERS 128
#define BPC 16             // blocks per cluster
#define BLOCK 256
#define NWAVE (BLOCK / 64)
#define MLP 8              // independent row-loads in flight per wave

// Workspace layout (d_ws):
//   int   offsets[N_CLUSTERS + 1]
//   float dxc[N_CLUSTERS]

__global__ void prep_kernel(const float* __restrict__ dx,
                            const int* __restrict__ sizes,
                            const float* __restrict__ dx_ranges,
                            int* __restrict__ offsets,
                            float* __restrict__ dxc) {
    __shared__ int s[N_CLUSTERS];
    const int t = threadIdx.x;      // 128 threads
    s[t] = sizes[t];
    float lo = dx_ranges[2 * t];
    float hi = dx_ranges[2 * t + 1];
    dxc[t] = fminf(fmaxf(dx[t], lo), hi);
    __syncthreads();
    int acc = 0;
    for (int i = 0; i < t; ++i) acc += s[i];
    offsets[t] = acc;
    if (t == N_CLUSTERS - 1) offsets[N_CLUSTERS] = acc + s[t];
}

__global__ __launch_bounds__(BLOCK) void gather_kernel(
    const float4* __restrict__ batch,
    const float4* __restrict__ vis4,
    const int*    __restrict__ offsets,
    const float*  __restrict__ dxc,
    float* __restrict__ out) {

    const int b     = blockIdx.x;
    const int c     = b / BPC;
    const int sub   = b % BPC;
    const int start = offsets[c];
    const int end   = offsets[c + 1];
    const int count = end - start;
    const int chunk = (count + BPC - 1) / BPC;
    const int s0 = start + sub * chunk;
    const int s1 = min(s0 + chunk, end);

    const int wave = threadIdx.x >> 6;
    const int lane = threadIdx.x & 63;

    const int wtotal = s1 - s0;
    const int per = (wtotal + NWAVE - 1) / NWAVE;
    const int ws0 = s0 + wave * per;
    const int ws1 = min(ws0 + per, s1);

    const float dxc_c = dxc[c];
    const bool active = (lane < N_PMT4);

    float4 accE = {0.f, 0.f, 0.f, 0.f};
    float4 accO = {0.f, 0.f, 0.f, 0.f};

    for (int base = ws0; base < ws1; base += 64) {
        const int p = base + lane;
        float q = 0.f;
        int vox = 0;
        if (p < ws1) {
            float4 pd = batch[p];
            float x = pd.x + dxc_c;
            int ix = (int)floorf(x);
            int iy = (int)floorf(pd.y);
            int iz = (int)floorf(pd.z);
            ix = max(0, min(63, ix));
            iy = max(0, min(63, iy));
            iz = max(0, min(63, iz));
            vox = ix + 64 * (iy + 64 * iz);
            q = pd.w;
        }
        #pragma unroll
        for (int j0 = 0; j0 < 64; j0 += MLP) {
            float4 r[MLP];
            float  qs[MLP];
            // broadcast q's into scalars (cheap, no memory dependence)
            #pragma unroll
            for (int jj = 0; jj < MLP; ++jj)
                qs[jj] = __uint_as_float(
                    __builtin_amdgcn_readlane(__float_as_uint(q), j0 + jj));
            if (active) {
                // issue all MLP independent row loads before consuming any
                #pragma unroll
                for (int jj = 0; jj < MLP; ++jj) {
                    const int v = __builtin_amdgcn_readlane(vox, j0 + jj);
                    r[jj] = vis4[(size_t)v * N_PMT4 + lane];
                }
                #pragma unroll
                for (int jj = 0; jj < MLP; ++jj) {
                    const float qq = qs[jj];
                    if (jj & 1) {
                        accO.x = fmaf(r[jj].x, qq, accO.x);
                        accO.y = fmaf(r[jj].y, qq, accO.y);
                        accO.z = fmaf(r[jj].z, qq, accO.z);
                        accO.w = fmaf(r[jj].w, qq, accO.w);
                    } else {
                        accE.x = fmaf(r[jj].x, qq, accE.x);
                        accE.y = fmaf(r[jj].y, qq, accE.y);
                        accE.z = fmaf(r[jj].z, qq, accE.z);
                        accE.w = fmaf(r[jj].w, qq, accE.w);
                    }
                }
            }
        }
    }

    // block-level reduction in LDS, then one atomic per PMT per block
    __shared__ float sacc[N_PMT];
    for (int i = threadIdx.x; i < N_PMT; i += BLOCK) sacc[i] = 0.f;
    __syncthreads();
    if (active) {
        atomicAdd(&sacc[lane * 4 + 0], accE.x + accO.x);
        atomicAdd(&sacc[lane * 4 + 1], accE.y + accO.y);
        atomicAdd(&sacc[lane * 4 + 2], accE.z + accO.z);
        atomicAdd(&sacc[lane * 4 + 3], accE.w + accO.w);
    }
    __syncthreads();
    for (int i = threadIdx.x; i < N_PMT; i += BLOCK)
        atomicAdd(&out[c * N_PMT + i], sacc[i]);
}

extern "C" void kernel_launch(void* const* d_in, const int* in_sizes, int n_in,
                              void* d_out, int out_size, void* d_ws, size_t ws_size,
                              hipStream_t stream) {
    const float* dx        = (const float*)d_in[0];
    const float* batch     = (const float*)d_in[1];
    const int*   sizes     = (const int*)d_in[2];
    const float* dx_ranges = (const float*)d_in[3];
    const float* vis       = (const float*)d_in[4];
    float* out = (float*)d_out;

    int*   offsets = (int*)d_ws;
    float* dxc     = (float*)((char*)d_ws + sizeof(int) * (N_CLUSTERS + 1));

    hipMemsetAsync(out, 0, (size_t)out_size * sizeof(float), stream);

    prep_kernel<<<1, N_CLUSTERS, 0, stream>>>(dx, sizes, dx_ranges, offsets, dxc);

    gather_kernel<<<N_CLUSTERS * BPC, BLOCK, 0, stream>>>(
        (const float4*)batch, (const float4*)vis, offsets, dxc, out);
}